// Round 3
// baseline (308.502 us; speedup 1.0000x reference)
//
#include <hip/hip_runtime.h>
#include <math.h>

#define NN 8000
#define NE 128000
#define NZ 10
#define KC 128
#define NB8 8
#define HID 64

// ws layout (float offsets)
#define WS_WL2R 0
#define WS_HUP  128
#define WS_WFIN 1408
#define WS_BASE 2688
#define WS_G    2704   // 100*64 floats -> end 9104 floats (36.4 KB)

__global__ __launch_bounds__(128)
void k_pre_a(const float* __restrict__ w_embed, const float* __restrict__ w_up,
             const float* __restrict__ w_lin,  const float* __restrict__ w_skip,
             const float* __restrict__ w_sym,  const float* __restrict__ w_lin2,
             const float* __restrict__ w_readout, const float* __restrict__ ae,
             float* __restrict__ ws)
{
    const int tid = threadIdx.x;   // 128 threads
    __shared__ float s_wl2r[KC];
    __shared__ float s_red[KC];

    // wl2r[k] = sum_j w_lin2[0][k][j] * w_readout[j]
    {
        const float* row = w_lin2 + tid * KC;
        float acc = 0.f;
        for (int j = 0; j < KC; ++j) acc += row[j] * w_readout[j];
        s_wl2r[tid] = acc;
    }
    __syncthreads();

    // h_up_s[z][k] = sum_kp w_embed[z][kp] * w_up[kp][k]
    for (int idx = tid; idx < NZ * KC; idx += 128) {
        const int z = idx >> 7, k = idx & 127;
        float acc = 0.f;
        for (int kp = 0; kp < KC; ++kp) acc += w_embed[z*KC + kp] * w_up[kp*KC + k];
        ws[WS_HUP + idx] = acc;
    }
    // Wfin[z][kp] = sum_k w_lin[0][kp][k] * w_sym[0][z][k] * wl2r[k]
    for (int idx = tid; idx < NZ * KC; idx += 128) {
        const int z = idx >> 7, kp = idx & 127;
        float acc = 0.f;
        for (int k = 0; k < KC; ++k) acc += w_lin[kp*KC + k] * w_sym[z*KC + k] * s_wl2r[k];
        ws[WS_WFIN + idx] = acc;
    }
    // base[z] = ae[z] + (1/sqrt(Z)) * sum_k w_embed[z][k] * (sum_j w_skip[z][k][j]*w_readout[j])
    const float rsz = rsqrtf((float)NZ);
    for (int z = 0; z < NZ; ++z) {
        const float* wk = w_skip + (z*KC + tid) * KC;
        float dot = 0.f;
        for (int j = 0; j < KC; ++j) dot += wk[j] * w_readout[j];
        s_red[tid] = w_embed[z*KC + tid] * dot;
        __syncthreads();
        if (tid == 0) {
            float ssum = 0.f;
            for (int i = 0; i < KC; ++i) ssum += s_red[i];
            ws[WS_BASE + z] = ae[z] + rsz * ssum;
        }
        __syncthreads();
    }
}

__global__ __launch_bounds__(64)
void k_pre_g(const float* __restrict__ W4, float* __restrict__ ws)
{
    const int pair = blockIdx.x;           // zs*10+zr, 100 blocks
    const int zs = pair / NZ, zr = pair % NZ;
    const int c = threadIdx.x;             // 64
    const float* hup   = ws + WS_HUP  + zs*KC;
    const float* wfin  = ws + WS_WFIN + zr*KC;
    const float* w4row = W4 + c * (KC*4);  // W4[c][:], take cols 4k (l=0)
    float acc = 0.f;
    for (int kp = 0; kp < KC; ++kp)
        acc += w4row[4*kp] * (hup[kp] * wfin[kp]);
    ws[WS_G + pair*HID + c] = acc * (1.0f/16.0f);  // fold /AVG_NEIGH
}

__global__ __launch_bounds__(256)
void k_init(const int* __restrict__ species, const float* __restrict__ ws,
            float* __restrict__ out)
{
    const int n = blockIdx.x * 256 + threadIdx.x;
    if (n < NN) out[n] = ws[WS_BASE + species[n]];
}

__global__ __launch_bounds__(256)
void k_edge(const float* __restrict__ pos, const float* __restrict__ shifts,
            const int* __restrict__ eidx, const int* __restrict__ species,
            const float* __restrict__ W1, const float* __restrict__ W2,
            const float* __restrict__ W3, const float* __restrict__ ws,
            float* __restrict__ out)
{
    __shared__ float sG[NZ*NZ*HID];               // 25.6 KB
    __shared__ __align__(16) float sT[4][HID];    // per-wave t broadcast row
    const int tid  = threadIdx.x;
    const int lane = tid & 63;
    const int wid  = tid >> 6;

    for (int i = tid; i < NZ*NZ*HID; i += 256) sG[i] = ws[WS_G + i];

    // per-lane weight columns in registers
    float w1r[NB8];
    #pragma unroll
    for (int b = 0; b < NB8; ++b) w1r[b] = W1[b*HID + lane];
    float w2r[HID], w3r[HID];
    #pragma unroll
    for (int c = 0; c < HID; ++c) w2r[c] = W2[c*HID + lane];
    #pragma unroll
    for (int c = 0; c < HID; ++c) w3r[c] = W3[c*HID + lane];
    __syncthreads();

    const int wtot = gridDim.x * 4;
    const int wg   = blockIdx.x * 4 + wid;

    for (int e = wg; e < NE; e += wtot) {
        const int sI = eidx[e];
        const int rI = eidx[NE + e];
        const float dx = pos[rI*3+0] - pos[sI*3+0] + shifts[e*3+0];
        const float dy = pos[rI*3+1] - pos[sI*3+1] + shifts[e*3+1];
        const float dz = pos[rI*3+2] - pos[sI*3+2] + shifts[e*3+2];
        const float r2 = dx*dx + dy*dy + dz*dz + 1e-9f;
        const float r  = sqrtf(r2);
        const float x  = r * 0.2f;                // r / R_MAX
        if (x >= 1.0f) continue;                  // env==0 -> contribution 0 (wave-uniform skip)

        // envelope: 1 - 21 x^5 + 35 x^6 - 15 x^7
        const float x2  = x*x;
        const float x5  = x2*x2*x;
        const float env = 1.0f + x5*(-21.0f + x*(35.0f - 15.0f*x));
        // bessel: sqrt(2/5) * sin(n*pi*x)/r * env via Chebyshev recurrence
        float s1, c1;
        __sincosf(3.14159265358979323846f * x, &s1, &c1);
        const float tc   = 2.0f * c1;
        const float pref = 0.632455532033675866f * env / r;

        // layer 1: 8 -> 64 (ef is lane-uniform, weights per-lane regs)
        float acc1 = 0.f;
        {
            float sp = 0.f, sc = s1;
            #pragma unroll
            for (int b = 0; b < NB8; ++b) {
                acc1 += (sc * pref) * w1r[b];
                const float nx = tc*sc - sp;
                sp = sc; sc = nx;
            }
        }
        const float t1 = acc1 / (1.0f + __expf(-acc1));

        __builtin_amdgcn_wave_barrier();
        sT[wid][lane] = t1;
        __builtin_amdgcn_wave_barrier();

        // layer 2: 64 -> 64
        float a0=0.f, a1=0.f, a2=0.f, a3=0.f;
        #pragma unroll
        for (int q = 0; q < 16; ++q) {
            const float4 tv = *reinterpret_cast<const float4*>(&sT[wid][q*4]);
            a0 += tv.x * w2r[4*q+0];
            a1 += tv.y * w2r[4*q+1];
            a2 += tv.z * w2r[4*q+2];
            a3 += tv.w * w2r[4*q+3];
        }
        const float z2v = (a0+a1)+(a2+a3);
        const float t2  = z2v / (1.0f + __expf(-z2v));

        __builtin_amdgcn_wave_barrier();
        sT[wid][lane] = t2;
        __builtin_amdgcn_wave_barrier();

        // layer 3: 64 -> 64
        a0=0.f; a1=0.f; a2=0.f; a3=0.f;
        #pragma unroll
        for (int q = 0; q < 16; ++q) {
            const float4 tv = *reinterpret_cast<const float4*>(&sT[wid][q*4]);
            a0 += tv.x * w3r[4*q+0];
            a1 += tv.y * w3r[4*q+1];
            a2 += tv.z * w3r[4*q+2];
            a3 += tv.w * w3r[4*q+3];
        }
        const float z3v = (a0+a1)+(a2+a3);
        const float t3  = z3v / (1.0f + __expf(-z3v));

        // contraction with per-species-pair vector + wave reduce
        const int zs = species[sI], zr = species[rI];
        float p = t3 * sG[(zs*NZ + zr)*HID + lane];
        #pragma unroll
        for (int off = 32; off > 0; off >>= 1) p += __shfl_xor(p, off);
        if (lane == 0) atomicAdd(&out[rI], p);
    }
}

extern "C" void kernel_launch(void* const* d_in, const int* in_sizes, int n_in,
                              void* d_out, int out_size, void* d_ws, size_t ws_size,
                              hipStream_t stream)
{
    const float* positions  = (const float*)d_in[0];
    const float* shifts     = (const float*)d_in[1];
    const int*   edge_index = (const int*)  d_in[2];
    const int*   species    = (const int*)  d_in[3];
    const float* ae         = (const float*)d_in[4];
    const float* w_embed    = (const float*)d_in[5];
    const float* w_up       = (const float*)d_in[6];
    const float* W1         = (const float*)d_in[7];
    const float* W2         = (const float*)d_in[8];
    const float* W3         = (const float*)d_in[9];
    const float* W4         = (const float*)d_in[10];
    const float* w_lin      = (const float*)d_in[11];
    const float* w_skip     = (const float*)d_in[12];
    const float* w_sym      = (const float*)d_in[13];
    const float* w_lin2     = (const float*)d_in[14];
    const float* w_readout  = (const float*)d_in[15];
    float* out = (float*)d_out;
    float* ws  = (float*)d_ws;

    k_pre_a<<<1, 128, 0, stream>>>(w_embed, w_up, w_lin, w_skip, w_sym, w_lin2,
                                   w_readout, ae, ws);
    k_pre_g<<<100, 64, 0, stream>>>(W4, ws);
    k_init<<<(NN + 255) / 256, 256, 0, stream>>>(species, ws, out);
    k_edge<<<1024, 256, 0, stream>>>(positions, shifts, edge_index, species,
                                     W1, W2, W3, ws, out);
}

// Round 4
// 196.368 us; speedup vs baseline: 1.5710x; 1.5710x over previous
//
#include <hip/hip_runtime.h>
#include <math.h>

#define NN 8000
#define NE 128000
#define NZ 10
#define KC 128
#define NB8 8
#define HID 64

// ws layout (float offsets)
#define WS_WL2R 0      // 128
#define WS_HUP  128    // 1280
#define WS_BASE 1408   // 10 (+pad)
#define WS_G    1424   // 100*64 = 6400 -> end 7824 floats (~31 KB)

// ---- precompute A: h_up (blocks 0..9), base (blocks 10..19), wl2r (block 20)
__global__ __launch_bounds__(256)
void kP1(const float* __restrict__ w_embed, const float* __restrict__ w_up,
         const float* __restrict__ w_skip, const float* __restrict__ w_lin2,
         const float* __restrict__ w_readout, const float* __restrict__ ae,
         float* __restrict__ ws)
{
    const int b = blockIdx.x, tid = threadIdx.x;
    if (b < NZ) {
        // h_up[b][k] = sum_kp w_embed[b][kp] * w_up[kp][k]
        if (tid < KC) {
            float acc = 0.f;
            for (int kp = 0; kp < KC; ++kp)
                acc += w_embed[b*KC + kp] * w_up[kp*KC + tid];
            ws[WS_HUP + b*KC + tid] = acc;
        }
    } else if (b < 2*NZ) {
        const int z = b - NZ;
        __shared__ float s_red[KC];
        if (tid < KC) {
            const float* wk = w_skip + (z*KC + tid)*KC;
            float dot = 0.f;
            for (int j = 0; j < KC; ++j) dot += wk[j] * w_readout[j];
            s_red[tid] = w_embed[z*KC + tid] * dot;
        }
        __syncthreads();
        for (int s = 64; s > 0; s >>= 1) {
            if (tid < s) s_red[tid] += s_red[tid + s];
            __syncthreads();
        }
        if (tid == 0) ws[WS_BASE + z] = ae[z] + rsqrtf((float)NZ) * s_red[0];
    } else {
        // wl2r[k] = sum_j w_lin2[0][k][j] * w_readout[j]
        if (tid < KC) {
            float acc = 0.f;
            for (int j = 0; j < KC; ++j) acc += w_lin2[tid*KC + j] * w_readout[j];
            ws[WS_WL2R + tid] = acc;
        }
    }
}

// ---- precompute G: one block per species pair; recompute wfin locally
__global__ __launch_bounds__(64)
void kG(const float* __restrict__ W4, const float* __restrict__ w_lin,
        const float* __restrict__ w_sym, float* __restrict__ ws)
{
    const int pair = blockIdx.x, zs = pair / NZ, zr = pair % NZ;
    const int tid = threadIdx.x;  // 64
    __shared__ float s_sw[KC];    // w_sym[0][zr][k] * wl2r[k]
    __shared__ float s_hw[KC];    // hup[zs][kp] * wfin[zr][kp]
    s_sw[tid]      = w_sym[zr*KC + tid]      * ws[WS_WL2R + tid];
    s_sw[tid + 64] = w_sym[zr*KC + tid + 64] * ws[WS_WL2R + tid + 64];
    __syncthreads();
    for (int kp = tid; kp < KC; kp += 64) {
        float acc = 0.f;
        for (int k = 0; k < KC; ++k) acc += w_lin[kp*KC + k] * s_sw[k];
        s_hw[kp] = ws[WS_HUP + zs*KC + kp] * acc;
    }
    __syncthreads();
    const float* w4row = W4 + tid * (KC*4);   // W4[c][4k] is l=0
    float acc = 0.f;
    for (int kp = 0; kp < KC; ++kp) acc += w4row[4*kp] * s_hw[kp];
    ws[WS_G + pair*HID + tid] = acc * (1.0f/16.0f);  // fold /AVG_NEIGH
}

__global__ __launch_bounds__(256)
void k_init(const int* __restrict__ species, const float* __restrict__ ws,
            float* __restrict__ out)
{
    const int n = blockIdx.x * 256 + threadIdx.x;
    if (n < NN) out[n] = ws[WS_BASE + species[n]];
}

// ---- main edge kernel: wave-per-edge, 2 edges per iteration for ILP
__global__ __launch_bounds__(256)
void k_edge(const float* __restrict__ pos, const float* __restrict__ shifts,
            const int* __restrict__ eidx, const int* __restrict__ species,
            const float* __restrict__ W1, const float* __restrict__ W2,
            const float* __restrict__ W3, const float* __restrict__ ws,
            float* __restrict__ out)
{
    __shared__ __align__(16) float sT[4][2][HID];   // per-wave, per-edge-slot
    const int tid  = threadIdx.x;
    const int lane = tid & 63;
    const int wid  = tid >> 6;

    float w1r[NB8];
    #pragma unroll
    for (int b = 0; b < NB8; ++b) w1r[b] = W1[b*HID + lane];
    float w2r[HID], w3r[HID];
    #pragma unroll
    for (int c = 0; c < HID; ++c) w2r[c] = W2[c*HID + lane];
    #pragma unroll
    for (int c = 0; c < HID; ++c) w3r[c] = W3[c*HID + lane];

    const float* G = ws + WS_G;
    const int wg   = blockIdx.x * 4 + wid;
    const int wtot = gridDim.x * 4;

    for (int e0 = wg * 2; e0 < NE; e0 += wtot * 2) {
        const int eA = e0, eB = e0 + 1;
        const int sA = eidx[eA], rA = eidx[NE + eA];
        const int sB = eidx[eB], rB = eidx[NE + eB];

        const float dxA = pos[rA*3+0] - pos[sA*3+0] + shifts[eA*3+0];
        const float dyA = pos[rA*3+1] - pos[sA*3+1] + shifts[eA*3+1];
        const float dzA = pos[rA*3+2] - pos[sA*3+2] + shifts[eA*3+2];
        const float dxB = pos[rB*3+0] - pos[sB*3+0] + shifts[eB*3+0];
        const float dyB = pos[rB*3+1] - pos[sB*3+1] + shifts[eB*3+1];
        const float dzB = pos[rB*3+2] - pos[sB*3+2] + shifts[eB*3+2];
        const float r2A = dxA*dxA + dyA*dyA + dzA*dzA + 1e-9f;
        const float r2B = dxB*dxB + dyB*dyB + dzB*dzB + 1e-9f;
        if (r2A >= 25.f && r2B >= 25.f) continue;   // wave-uniform: both dead

        const float rA_ = sqrtf(r2A), rB_ = sqrtf(r2B);
        const float xA = rA_ * 0.2f,  xB = rB_ * 0.2f;

        // envelope (0 for dead edge -> whole chain exactly 0)
        float envA = 0.f, envB = 0.f;
        {
            const float x2 = xA*xA, x5 = x2*x2*xA;
            if (xA < 1.f) envA = 1.0f + x5*(-21.0f + xA*(35.0f - 15.0f*xA));
        }
        {
            const float x2 = xB*xB, x5 = x2*x2*xB;
            if (xB < 1.f) envB = 1.0f + x5*(-21.0f + xB*(35.0f - 15.0f*xB));
        }
        float s1A, c1A, s1B, c1B;
        __sincosf(3.14159265358979323846f * xA, &s1A, &c1A);
        __sincosf(3.14159265358979323846f * xB, &s1B, &c1B);
        const float tcA = 2.f*c1A, tcB = 2.f*c1B;
        const float prefA = 0.632455532033675866f * envA / rA_;
        const float prefB = 0.632455532033675866f * envB / rB_;

        // layer 1 (8->64), Chebyshev recurrence for sin(n*pi*x)
        float accA = 0.f, accB = 0.f;
        {
            float spA = 0.f, scA = s1A, spB = 0.f, scB = s1B;
            #pragma unroll
            for (int b = 0; b < NB8; ++b) {
                accA += (scA * prefA) * w1r[b];
                accB += (scB * prefB) * w1r[b];
                const float nA = tcA*scA - spA; spA = scA; scA = nA;
                const float nB = tcB*scB - spB; spB = scB; scB = nB;
            }
        }
        const float t1A = accA / (1.0f + __expf(-accA));
        const float t1B = accB / (1.0f + __expf(-accB));

        __builtin_amdgcn_wave_barrier();
        sT[wid][0][lane] = t1A;
        sT[wid][1][lane] = t1B;
        __builtin_amdgcn_wave_barrier();

        // layer 2 (64->64), both edges interleaved
        float a0A=0.f,a1A=0.f,a2A=0.f,a3A=0.f, a0B=0.f,a1B=0.f,a2B=0.f,a3B=0.f;
        #pragma unroll
        for (int q = 0; q < 16; ++q) {
            const float4 tA = *reinterpret_cast<const float4*>(&sT[wid][0][q*4]);
            const float4 tB = *reinterpret_cast<const float4*>(&sT[wid][1][q*4]);
            a0A += tA.x * w2r[4*q+0]; a0B += tB.x * w2r[4*q+0];
            a1A += tA.y * w2r[4*q+1]; a1B += tB.y * w2r[4*q+1];
            a2A += tA.z * w2r[4*q+2]; a2B += tB.z * w2r[4*q+2];
            a3A += tA.w * w2r[4*q+3]; a3B += tB.w * w2r[4*q+3];
        }
        const float z2A = (a0A+a1A)+(a2A+a3A);
        const float z2B = (a0B+a1B)+(a2B+a3B);
        const float t2A = z2A / (1.0f + __expf(-z2A));
        const float t2B = z2B / (1.0f + __expf(-z2B));

        __builtin_amdgcn_wave_barrier();
        sT[wid][0][lane] = t2A;
        sT[wid][1][lane] = t2B;
        __builtin_amdgcn_wave_barrier();

        // layer 3 (64->64)
        a0A=0.f;a1A=0.f;a2A=0.f;a3A=0.f; a0B=0.f;a1B=0.f;a2B=0.f;a3B=0.f;
        #pragma unroll
        for (int q = 0; q < 16; ++q) {
            const float4 tA = *reinterpret_cast<const float4*>(&sT[wid][0][q*4]);
            const float4 tB = *reinterpret_cast<const float4*>(&sT[wid][1][q*4]);
            a0A += tA.x * w3r[4*q+0]; a0B += tB.x * w3r[4*q+0];
            a1A += tA.y * w3r[4*q+1]; a1B += tB.y * w3r[4*q+1];
            a2A += tA.z * w3r[4*q+2]; a2B += tB.z * w3r[4*q+2];
            a3A += tA.w * w3r[4*q+3]; a3B += tB.w * w3r[4*q+3];
        }
        const float z3A = (a0A+a1A)+(a2A+a3A);
        const float z3B = (a0B+a1B)+(a2B+a3B);
        const float t3A = z3A / (1.0f + __expf(-z3A));
        const float t3B = z3B / (1.0f + __expf(-z3B));

        // per-pair G row (coalesced dword, L1-resident 25.6 KB table)
        const int pA = species[sA]*NZ + species[rA];
        const int pB = species[sB]*NZ + species[rB];
        float vA = t3A * G[pA*HID + lane];
        float vB = t3B * G[pB*HID + lane];
        #pragma unroll
        for (int off = 32; off > 0; off >>= 1) {
            vA += __shfl_xor(vA, off);
            vB += __shfl_xor(vB, off);
        }
        if (lane == 0) {
            atomicAdd(&out[rA], vA);
            atomicAdd(&out[rB], vB);
        }
    }
}

extern "C" void kernel_launch(void* const* d_in, const int* in_sizes, int n_in,
                              void* d_out, int out_size, void* d_ws, size_t ws_size,
                              hipStream_t stream)
{
    const float* positions  = (const float*)d_in[0];
    const float* shifts     = (const float*)d_in[1];
    const int*   edge_index = (const int*)  d_in[2];
    const int*   species    = (const int*)  d_in[3];
    const float* ae         = (const float*)d_in[4];
    const float* w_embed    = (const float*)d_in[5];
    const float* w_up       = (const float*)d_in[6];
    const float* W1         = (const float*)d_in[7];
    const float* W2         = (const float*)d_in[8];
    const float* W3         = (const float*)d_in[9];
    const float* W4         = (const float*)d_in[10];
    const float* w_lin      = (const float*)d_in[11];
    const float* w_skip     = (const float*)d_in[12];
    const float* w_sym      = (const float*)d_in[13];
    const float* w_lin2     = (const float*)d_in[14];
    const float* w_readout  = (const float*)d_in[15];
    float* out = (float*)d_out;
    float* ws  = (float*)d_ws;

    kP1<<<2*NZ + 1, 256, 0, stream>>>(w_embed, w_up, w_skip, w_lin2, w_readout, ae, ws);
    kG<<<NZ*NZ, 64, 0, stream>>>(W4, w_lin, w_sym, ws);
    k_init<<<(NN + 255)/256, 256, 0, stream>>>(species, ws, out);
    k_edge<<<2048, 256, 0, stream>>>(positions, shifts, edge_index, species,
                                     W1, W2, W3, ws, out);
}